// Round 7
// baseline (84.233 us; speedup 1.0000x reference)
//
#include <hip/hip_runtime.h>
#include <hip/hip_bf16.h>
#include <cstdint>
#include <cstddef>

#define B_ROWS 8192
#define KDIM   4096
#define IN_DIM 2048
#define HIDDEN 2048
#define NJ     32           // 4 gates x 8 wires
#define KC     8            // K-split across blocks
#define CHUNK  (KDIM / KC)  // 512
#define BK     128          // k-subtile staged in LDS
#define SUBT   (CHUNK / BK) // 4
#define MROWS  32           // rows per block
#define TPB1   128          // 2 waves
#define AP     136          // padded LDS pitch in bf16 (128 + 8)

typedef __bf16 bf16x8 __attribute__((ext_vector_type(8)));
typedef __bf16 bf16x4 __attribute__((ext_vector_type(4)));
typedef float  f32x4  __attribute__((ext_vector_type(4)));

// ---------------- Pass 0: pack weights to bf16 [32][4096]; zero q ---------
extern "C" __global__ __launch_bounds__(256)
void w_pack(const float* __restrict__ Wf, const float* __restrict__ Wi,
            const float* __restrict__ Wg, const float* __restrict__ Wo,
            __bf16* __restrict__ Wb, float* __restrict__ q)
{
    if (blockIdx.x == 0 && threadIdx.x < 4) q[threadIdx.x] = 0.f;

    const int t    = blockIdx.x * 256 + threadIdx.x;   // 0 .. 32767
    const int idx4 = t << 2;
    const int j    = idx4 >> 12;
    const int k    = idx4 & (KDIM - 1);
    const float* W = (j < 8) ? Wf : (j < 16) ? Wi : (j < 24) ? Wg : Wo;
    f32x4 v = *reinterpret_cast<const f32x4*>(W + (size_t)(j & 7) * KDIM + k);
    bf16x4 b;
    b[0] = (__bf16)v.x; b[1] = (__bf16)v.y; b[2] = (__bf16)v.z; b[3] = (__bf16)v.w;
    *reinterpret_cast<bf16x4*>(Wb + idx4) = b;
}

// ---------------- Pass 1: split-K MFMA GEMM, prefetched LDS pipeline ------
// grid = 256 mblocks * 8 kc; block = 128 thr (2 waves) = 32 rows x 512 k.
// Spart layout: [KC][B_ROWS][NJ]
extern "C" __global__ __launch_bounds__(TPB1)
void p1_mfma(const float* __restrict__ x, const float* __restrict__ hx,
             const __bf16* __restrict__ Wb, float* __restrict__ Spart)
{
    __shared__ __bf16 At[2][MROWS * AP];   // 2 x 8,704 B

    const int bid  = blockIdx.x;
    const int kc   = bid & (KC - 1);
    const int mb   = bid >> 3;                  // 0..255
    const int tid  = threadIdx.x;
    const int wave = tid >> 6;
    const int lane = tid & 63;
    const int lrow = lane & 15;                 // frag row / B col
    const int koff = (lane >> 4) * 8;           // 8 consecutive k per lane
    const int rowblk = mb * MROWS;
    const int k0   = kc * CHUNK;

    // x and hx share row stride 2048; a 512-chunk never straddles them
    const float* Asrc = (kc < 4)
        ? (x  + (size_t)rowblk * IN_DIM + k0)
        : (hx + (size_t)rowblk * HIDDEN + (k0 - IN_DIM));
    const __bf16* Bsrc = Wb + (size_t)lrow * KDIM + k0 + koff;

    f32x4  pa[2][8];     // A prefetch regs (fp32)
    bf16x8 pbf[2][8];    // B prefetch regs (bf16)
    f32x4  acc0 = {0.f, 0.f, 0.f, 0.f};
    f32x4  acc1 = {0.f, 0.f, 0.f, 0.f};

    // NOTE on vmcnt FIFO: per subtile we issue B first, then A. Consuming
    // A(sub)/B(sub) therefore never forces the (sub+1) batch to complete.
    auto issueB = [&](int b, int sub) {
#pragma unroll
        for (int st = 0; st < 4; ++st) {
            pbf[b][st * 2]     = *reinterpret_cast<const bf16x8*>(
                Bsrc + sub * BK + st * 32);
            pbf[b][st * 2 + 1] = *reinterpret_cast<const bf16x8*>(
                Bsrc + (size_t)16 * KDIM + sub * BK + st * 32);
        }
    };
    auto issueA = [&](int b, int sub) {
#pragma unroll
        for (int p = 0; p < 8; ++p) {
            const int slot = p * TPB1 + tid;    // 0..1023
            const int r    = slot >> 5;         // row 0..31
            const int c4   = slot & 31;         // f32x4 index in 128-float row
            pa[b][p] = __builtin_nontemporal_load(
                reinterpret_cast<const f32x4*>(Asrc + (size_t)r * 2048 + sub * BK) + c4);
        }
    };
    auto stage = [&](int b) {
#pragma unroll
        for (int p = 0; p < 8; ++p) {
            const int slot = p * TPB1 + tid;
            const int r    = slot >> 5;
            const int c4   = slot & 31;
            f32x4 v = pa[b][p];
            bf16x4 w;
            w[0] = (__bf16)v.x; w[1] = (__bf16)v.y;
            w[2] = (__bf16)v.z; w[3] = (__bf16)v.w;
            *reinterpret_cast<bf16x4*>(&At[b][r * AP + c4 * 4]) = w;
        }
    };
    auto compute = [&](int b) {
#pragma unroll
        for (int st = 0; st < 4; ++st) {
            bf16x8 af = *reinterpret_cast<const bf16x8*>(
                &At[b][(wave * 16 + lrow) * AP + st * 32 + koff]);
            acc0 = __builtin_amdgcn_mfma_f32_16x16x32_bf16(af, pbf[b][st * 2],     acc0, 0, 0, 0);
            acc1 = __builtin_amdgcn_mfma_f32_16x16x32_bf16(af, pbf[b][st * 2 + 1], acc1, 0, 0, 0);
        }
    };

    issueB(0, 0);
    issueA(0, 0);
#pragma unroll
    for (int sub = 0; sub < SUBT; ++sub) {
        const int b = sub & 1;
        if (sub + 1 < SUBT) {          // prefetch next subtile (stays in
            issueB(b ^ 1, sub + 1);    // flight across the raw barrier)
            issueA(b ^ 1, sub + 1);
        }
        stage(b);                      // waits vmcnt for batch sub only
        // drain LDS writes, but NOT vmcnt: raw barrier keeps prefetch alive
        asm volatile("s_waitcnt lgkmcnt(0)" ::: "memory");
        __builtin_amdgcn_s_barrier();
        asm volatile("" ::: "memory"); // fence: no ds_read hoist above barrier
        compute(b);
        // buffer reuse safe: a wave writing At[b] at iter s passed barrier
        // s-1, which every wave reached only after its iter s-2 reads of
        // At[b] completed (MFMA consumed them before its iter s-1 ds_writes).
    }

    // D layout (16x16x32): col = lane&15, row = (lane>>4)*4 + reg
    const int row0 = rowblk + wave * 16;
    float* sp = Spart + ((size_t)kc * B_ROWS + row0) * NJ;
    const int m0 = (lane >> 4) * 4;
#pragma unroll
    for (int r = 0; r < 4; ++r) {
        sp[(size_t)(m0 + r) * NJ + lrow]      = acc0[r];
        sp[(size_t)(m0 + r) * NJ + 16 + lrow] = acc1[r];
    }
}

// ---------------- Pass 2: sum partials, bias, cos, reduce to q[4] ----------
// grid = 256 blocks * 256 thr = 65536 threads; each thread: 4 (row,j) pairs
extern "C" __global__ __launch_bounds__(256)
void p2_cos_reduce(const float* __restrict__ Spart,
                   const float* __restrict__ bf, const float* __restrict__ bi,
                   const float* __restrict__ bg, const float* __restrict__ bo,
                   float* __restrict__ q)
{
    __shared__ float ql[4];
    if (threadIdx.x < 4) ql[threadIdx.x] = 0.f;
    __syncthreads();

    const int t    = blockIdx.x * 256 + threadIdx.x;  // 0..65535
    const int j    = t & 31;
    const int gate = j >> 3;
    const float* Bp = (gate == 0) ? bf : (gate == 1) ? bi : (gate == 2) ? bg : bo;
    const float bj = Bp[j & 7];

    float accg = 0.f;
#pragma unroll
    for (int i = 0; i < 4; ++i) {
        const int row = (t >> 5) + i * 2048;
        float s = 0.f;
#pragma unroll
        for (int kc = 0; kc < KC; ++kc)
            s += Spart[((size_t)kc * B_ROWS + row) * NJ + j];
        accg += cosf(s + bj);
    }

    accg += __shfl_xor(accg, 1, 64);
    accg += __shfl_xor(accg, 2, 64);
    accg += __shfl_xor(accg, 4, 64);
    if ((threadIdx.x & 7) == 0) atomicAdd(&ql[gate], accg);
    __syncthreads();
    if (threadIdx.x < 4) atomicAdd(&q[threadIdx.x], ql[threadIdx.x]);
}

// ---------------- Pass 3: elementwise LSTM update ----------------
extern "C" __global__ __launch_bounds__(256)
void p3_elementwise(const float* __restrict__ cx, const float* __restrict__ q,
                    float* __restrict__ out)
{
    const float qf = q[0], qi = q[1], qg = q[2], qo = q[3];
    const float f  = 1.f / (1.f + expf(-qf));
    const float ii = 1.f / (1.f + expf(-qi));
    const float g  = tanhf(qg);
    const float o  = 1.f / (1.f + expf(-qo));
    const float ig = ii * g;

    const size_t N  = (size_t)B_ROWS * HIDDEN;
    const size_t N4 = N >> 2;
    const f32x4* cx4 = (const f32x4*)cx;
    f32x4* outh = (f32x4*)out;
    f32x4* outc = (f32x4*)(out + N);

    for (size_t idx = (size_t)blockIdx.x * blockDim.x + threadIdx.x; idx < N4;
         idx += (size_t)gridDim.x * blockDim.x) {
        f32x4 c = __builtin_nontemporal_load(cx4 + idx);  // streaming, no reuse
        f32x4 cn, hn;
        cn.x = fmaf(f, c.x, ig);
        cn.y = fmaf(f, c.y, ig);
        cn.z = fmaf(f, c.z, ig);
        cn.w = fmaf(f, c.w, ig);
        hn.x = o * tanhf(cn.x);
        hn.y = o * tanhf(cn.y);
        hn.z = o * tanhf(cn.z);
        hn.w = o * tanhf(cn.w);
        outc[idx] = cn;
        outh[idx] = hn;
    }
}

// ---------------- launcher ----------------
extern "C" void kernel_launch(void* const* d_in, const int* in_sizes, int n_in,
                              void* d_out, int out_size, void* d_ws, size_t ws_size,
                              hipStream_t stream)
{
    const float* x  = (const float*)d_in[0];
    const float* hx = (const float*)d_in[1];
    const float* cx = (const float*)d_in[2];
    const float* Wf = (const float*)d_in[3];
    const float* bf = (const float*)d_in[4];
    const float* Wi = (const float*)d_in[5];
    const float* bi = (const float*)d_in[6];
    const float* Wg = (const float*)d_in[7];
    const float* bg = (const float*)d_in[8];
    const float* Wo = (const float*)d_in[9];
    const float* bo = (const float*)d_in[10];
    float* out = (float*)d_out;

    // ws layout: Spart [KC][8192][32] f32 (8 MB) | Wb [32][4096] bf16 (256 KB) | q[4]
    float*   Spart = (float*)d_ws;
    __bf16*  Wb    = (__bf16*)(Spart + (size_t)KC * B_ROWS * NJ);
    float*   q     = (float*)(Wb + (size_t)NJ * KDIM);

    w_pack<<<dim3(128), dim3(256), 0, stream>>>(Wf, Wi, Wg, Wo, Wb, q);
    p1_mfma<<<dim3(256 * KC), dim3(TPB1), 0, stream>>>(x, hx, Wb, Spart);
    p2_cos_reduce<<<dim3(256), dim3(256), 0, stream>>>(Spart, bf, bi, bg, bo, q);
    p3_elementwise<<<dim3(2048), dim3(256), 0, stream>>>(cx, q, out);
}

// Round 8
// 76.296 us; speedup vs baseline: 1.1040x; 1.1040x over previous
//
#include <hip/hip_runtime.h>
#include <hip/hip_bf16.h>
#include <cstdint>
#include <cstddef>

#define B_ROWS 8192
#define KDIM   4096
#define IN_DIM 2048
#define HIDDEN 2048
#define NJ     32           // 4 gates x 8 wires
#define KC     8            // K-split across blocks
#define CHUNK  (KDIM / KC)  // 512
#define BK     64           // k-subtile per pipeline stage
#define SUBT   (CHUNK / BK) // 8
#define MROWS  64           // rows per block (4 waves x 16)
#define NBUF   4            // pipeline buffers (depth-2 prefetch, race-free)

typedef __bf16 bf16x8 __attribute__((ext_vector_type(8)));
typedef __bf16 bf16x4 __attribute__((ext_vector_type(4)));
typedef float  f32x4  __attribute__((ext_vector_type(4)));

__device__ __forceinline__ bf16x8 cvt8(f32x4 a, f32x4 b) {
    bf16x8 r;
    r[0] = (__bf16)a.x; r[1] = (__bf16)a.y; r[2] = (__bf16)a.z; r[3] = (__bf16)a.w;
    r[4] = (__bf16)b.x; r[5] = (__bf16)b.y; r[6] = (__bf16)b.z; r[7] = (__bf16)b.w;
    return r;
}

// async global->LDS, 16 B per lane; LDS dest = wave-uniform base + lane*16
__device__ __forceinline__ void gload_lds16(const void* g, void* lds) {
    __builtin_amdgcn_global_load_lds(
        (const __attribute__((address_space(1))) void*)g,
        (__attribute__((address_space(3))) void*)lds, 16, 0, 0);
}

// ---------------- Pass 0: pack weights to bf16 [32][4096]; zero q ---------
extern "C" __global__ __launch_bounds__(256)
void w_pack(const float* __restrict__ Wf, const float* __restrict__ Wi,
            const float* __restrict__ Wg, const float* __restrict__ Wo,
            __bf16* __restrict__ Wb, float* __restrict__ q)
{
    if (blockIdx.x == 0 && threadIdx.x < 4) q[threadIdx.x] = 0.f;

    const int t    = blockIdx.x * 256 + threadIdx.x;   // 0 .. 32767
    const int idx4 = t << 2;
    const int j    = idx4 >> 12;
    const int k    = idx4 & (KDIM - 1);
    const float* W = (j < 8) ? Wf : (j < 16) ? Wi : (j < 24) ? Wg : Wo;
    f32x4 v = *reinterpret_cast<const f32x4*>(W + (size_t)(j & 7) * KDIM + k);
    bf16x4 b;
    b[0] = (__bf16)v.x; b[1] = (__bf16)v.y; b[2] = (__bf16)v.z; b[3] = (__bf16)v.w;
    *reinterpret_cast<bf16x4*>(Wb + idx4) = b;
}

// ------- Pass 1: split-K MFMA GEMM, global_load_lds + counted-vmcnt -------
// grid = 128 mblocks * 8 kc; block = 256 thr (4 waves) = 64 rows x 512 k.
// LDS: A fp32 [NBUF][64][64] (16 KB/buf), B bf16 [NBUF][32][64] (4 KB/buf).
// XOR swizzle (both sides): 16B-unit index cu ^= (row & 7).
// Spart layout: [KC][B_ROWS][NJ]
extern "C" __global__ __launch_bounds__(256)
void p1_mfma(const float* __restrict__ x, const float* __restrict__ hx,
             const __bf16* __restrict__ Wb, float* __restrict__ Spart)
{
    __shared__ float  Abuf[NBUF][MROWS * BK];   // 4 x 16 KB
    __shared__ __bf16 Bbuf[NBUF][NJ * BK];      // 4 x 4 KB

    const int bid  = blockIdx.x;
    const int kc   = bid & (KC - 1);
    const int mb   = bid >> 3;                  // 0..127
    const int tid  = threadIdx.x;
    const int wave = tid >> 6;
    const int lane = tid & 63;
    const int rowblk = mb * MROWS;
    const int k0   = kc * CHUNK;

    // ---- global sources (x / hx share row stride 2048; chunk never straddles)
    const float* Aglob = (kc < 4)
        ? (x  + (size_t)rowblk * IN_DIM + k0)
        : (hx + (size_t)rowblk * HIDDEN + (k0 - IN_DIM));
    const __bf16* Bglob = Wb + k0;

    // ---- staging addresses (pre-swizzled global source, rule #21) ----
    // A instr (wave,p): LDS rows R..R+3 linear; lane l -> row R+(l>>4), cu l&15.
    // Source element = (row, (l&15) ^ (row&7)); wave*16 === 0 (mod 8).
    int aOff[4];
#pragma unroll
    for (int p = 0; p < 4; ++p) {
        const int r  = wave * 16 + p * 4 + (lane >> 4);
        const int cs = (lane & 15) ^ ((p * 4 + (lane >> 4)) & 7);
        aOff[p] = r * 2048 + cs * 4;            // float offset
    }
    // B instr (one per wave): j = wave*8 + (l>>3), cu = l&7, src cu ^= (j&7)
    const int bj   = wave * 8 + (lane >> 3);
    const int bOff = bj * KDIM + (((lane & 7) ^ ((lane >> 3) & 7)) * 8); // bf16 off

    // ---- read addresses (swizzled ds_read_b128), precomputed bytes ----
    const int lrow  = lane & 15;
    const int row_r = wave * 16 + lrow;          // A row (wave-private)
    int offA0[2], offA1[2], offB0[2], offB1[2];
#pragma unroll
    for (int st = 0; st < 2; ++st) {
        const int cu = st * 8 + (lane >> 4) * 2;            // A 16B-unit
        offA0[st] = row_r * 256 + ((cu + 0) ^ (lane & 7)) * 16;
        offA1[st] = row_r * 256 + ((cu + 1) ^ (lane & 7)) * 16;
        const int cb = st * 4 + (lane >> 4);                // B 16B-unit
        offB0[st] = lrow * 128        + (cb ^ (lrow & 7)) * 16;
        offB1[st] = (lrow + 16) * 128 + (cb ^ (lrow & 7)) * 16;
    }

    f32x4 acc0 = {0.f, 0.f, 0.f, 0.f};
    f32x4 acc1 = {0.f, 0.f, 0.f, 0.f};

    auto issue = [&](int s) {
        const int b = s & (NBUF - 1);
#pragma unroll
        for (int p = 0; p < 4; ++p)
            gload_lds16(Aglob + aOff[p] + s * BK, &Abuf[b][(wave * 4 + p) * 256]);
        gload_lds16(Bglob + bOff + s * BK, &Bbuf[b][wave * 512]);
    };
    auto compute = [&](int s) {
        const int b = s & (NBUF - 1);
        const char* Ab = (const char*)&Abuf[b][0];
        const char* Bb = (const char*)&Bbuf[b][0];
#pragma unroll
        for (int st = 0; st < 2; ++st) {
            f32x4 a0 = *reinterpret_cast<const f32x4*>(Ab + offA0[st]);
            f32x4 a1 = *reinterpret_cast<const f32x4*>(Ab + offA1[st]);
            bf16x8 af = cvt8(a0, a1);
            bf16x8 b0 = *reinterpret_cast<const bf16x8*>(Bb + offB0[st]);
            bf16x8 b1 = *reinterpret_cast<const bf16x8*>(Bb + offB1[st]);
            acc0 = __builtin_amdgcn_mfma_f32_16x16x32_bf16(af, b0, acc0, 0, 0, 0);
            acc1 = __builtin_amdgcn_mfma_f32_16x16x32_bf16(af, b1, acc1, 0, 0, 0);
        }
    };

    // ---- pipeline: depth-2 prefetch, counted vmcnt, raw barriers ----
    // vmcnt math: 5 loads/batch; after issue(s+2), outstanding = {s+1,s+2}=10
    // -> vmcnt(10) implies batch s landed. Tail: s=6 -> 5, s=7 -> 0.
    issue(0);
    issue(1);
#pragma unroll
    for (int s = 0; s < SUBT; ++s) {
        if (s + 2 < SUBT) issue(s + 2);
        if (s < SUBT - 2)
            asm volatile("s_waitcnt vmcnt(10)" ::: "memory");
        else if (s == SUBT - 2)
            asm volatile("s_waitcnt vmcnt(5)" ::: "memory");
        else
            asm volatile("s_waitcnt vmcnt(0)" ::: "memory");
        __builtin_amdgcn_s_barrier();           // all waves' batch-s writes done
        __builtin_amdgcn_sched_barrier(0);      // no ds_read hoist (rule #18)
        compute(s);
        // reuse safety: writes at iter s target buf (s+2)%4; slowest concurrent
        // reader is at compute(s-1) on buf (s-1)%4 -- distance 3 mod 4 != 0.
    }

    // D layout (16x16x32): col = lane&15, row = (lane>>4)*4 + reg
    const int row0 = rowblk + wave * 16;
    float* sp = Spart + ((size_t)kc * B_ROWS + row0) * NJ;
    const int m0 = (lane >> 4) * 4;
#pragma unroll
    for (int r = 0; r < 4; ++r) {
        sp[(size_t)(m0 + r) * NJ + lrow]      = acc0[r];
        sp[(size_t)(m0 + r) * NJ + 16 + lrow] = acc1[r];
    }
}

// ---------------- Pass 2: sum partials, bias, cos, reduce to q[4] ----------
// grid = 256 blocks * 256 thr = 65536 threads; each thread: 4 (row,j) pairs
extern "C" __global__ __launch_bounds__(256)
void p2_cos_reduce(const float* __restrict__ Spart,
                   const float* __restrict__ bf, const float* __restrict__ bi,
                   const float* __restrict__ bg, const float* __restrict__ bo,
                   float* __restrict__ q)
{
    __shared__ float ql[4];
    if (threadIdx.x < 4) ql[threadIdx.x] = 0.f;
    __syncthreads();

    const int t    = blockIdx.x * 256 + threadIdx.x;  // 0..65535
    const int j    = t & 31;
    const int gate = j >> 3;
    const float* Bp = (gate == 0) ? bf : (gate == 1) ? bi : (gate == 2) ? bg : bo;
    const float bj = Bp[j & 7];

    float accg = 0.f;
#pragma unroll
    for (int i = 0; i < 4; ++i) {
        const int row = (t >> 5) + i * 2048;
        float s = 0.f;
#pragma unroll
        for (int kc = 0; kc < KC; ++kc)
            s += Spart[((size_t)kc * B_ROWS + row) * NJ + j];
        accg += cosf(s + bj);
    }

    accg += __shfl_xor(accg, 1, 64);
    accg += __shfl_xor(accg, 2, 64);
    accg += __shfl_xor(accg, 4, 64);
    if ((threadIdx.x & 7) == 0) atomicAdd(&ql[gate], accg);
    __syncthreads();
    if (threadIdx.x < 4) atomicAdd(&q[threadIdx.x], ql[threadIdx.x]);
}

// ---------------- Pass 3: elementwise LSTM update ----------------
extern "C" __global__ __launch_bounds__(256)
void p3_elementwise(const float* __restrict__ cx, const float* __restrict__ q,
                    float* __restrict__ out)
{
    const float qf = q[0], qi = q[1], qg = q[2], qo = q[3];
    const float f  = 1.f / (1.f + expf(-qf));
    const float ii = 1.f / (1.f + expf(-qi));
    const float g  = tanhf(qg);
    const float o  = 1.f / (1.f + expf(-qo));
    const float ig = ii * g;

    const size_t N  = (size_t)B_ROWS * HIDDEN;
    const size_t N4 = N >> 2;
    const f32x4* cx4 = (const f32x4*)cx;
    f32x4* outh = (f32x4*)out;
    f32x4* outc = (f32x4*)(out + N);

    for (size_t idx = (size_t)blockIdx.x * blockDim.x + threadIdx.x; idx < N4;
         idx += (size_t)gridDim.x * blockDim.x) {
        f32x4 c = __builtin_nontemporal_load(cx4 + idx);  // streaming, no reuse
        f32x4 cn, hn;
        cn.x = fmaf(f, c.x, ig);
        cn.y = fmaf(f, c.y, ig);
        cn.z = fmaf(f, c.z, ig);
        cn.w = fmaf(f, c.w, ig);
        hn.x = o * tanhf(cn.x);
        hn.y = o * tanhf(cn.y);
        hn.z = o * tanhf(cn.z);
        hn.w = o * tanhf(cn.w);
        outc[idx] = cn;
        outh[idx] = hn;
    }
}

// ---------------- launcher ----------------
extern "C" void kernel_launch(void* const* d_in, const int* in_sizes, int n_in,
                              void* d_out, int out_size, void* d_ws, size_t ws_size,
                              hipStream_t stream)
{
    const float* x  = (const float*)d_in[0];
    const float* hx = (const float*)d_in[1];
    const float* cx = (const float*)d_in[2];
    const float* Wf = (const float*)d_in[3];
    const float* bf = (const float*)d_in[4];
    const float* Wi = (const float*)d_in[5];
    const float* bi = (const float*)d_in[6];
    const float* Wg = (const float*)d_in[7];
    const float* bg = (const float*)d_in[8];
    const float* Wo = (const float*)d_in[9];
    const float* bo = (const float*)d_in[10];
    float* out = (float*)d_out;

    // ws layout: Spart [KC][8192][32] f32 (8 MB) | Wb [32][4096] bf16 (256 KB) | q[4]
    float*   Spart = (float*)d_ws;
    __bf16*  Wb    = (__bf16*)(Spart + (size_t)KC * B_ROWS * NJ);
    float*   q     = (float*)(Wb + (size_t)NJ * KDIM);

    w_pack<<<dim3(128), dim3(256), 0, stream>>>(Wf, Wi, Wg, Wo, Wb, q);
    p1_mfma<<<dim3(128 * KC), dim3(256), 0, stream>>>(x, hx, Wb, Spart);
    p2_cos_reduce<<<dim3(256), dim3(256), 0, stream>>>(Spart, bf, bi, bg, bo, q);
    p3_elementwise<<<dim3(2048), dim3(256), 0, stream>>>(cx, q, out);
}